// Round 1
// baseline (540.268 us; speedup 1.0000x reference)
//
#include <hip/hip_runtime.h>
#include <math.h>

#define WPB 4   // waves per block
#define RG  8   // rows register-blocked per wave

__device__ __forceinline__ int dot4(int a, int b, int c) {
#if defined(__has_builtin)
#if __has_builtin(__builtin_amdgcn_sdot4)
    return __builtin_amdgcn_sdot4(a, b, c, false);
#define DOT4_DONE 1
#endif
#endif
#ifndef DOT4_DONE
    int r = c;
    r += ((a << 24) >> 24) * ((b << 24) >> 24);
    r += ((a << 16) >> 24) * ((b << 16) >> 24);
    r += ((a <<  8) >> 24) * ((b <<  8) >> 24);
    r += ( a        >> 24) * ( b        >> 24);
    return r;
#endif
}

__device__ __forceinline__ float sigmoidf_(float v) {
    return 1.0f / (1.0f + __expf(-v));
}

__global__ __launch_bounds__(256, 3)
void mlgru_kernel(const float* __restrict__ x,
                  const float* __restrict__ hprev,
                  const float* __restrict__ Wf,
                  const float* __restrict__ Wc,
                  const float* __restrict__ Wg,
                  const float* __restrict__ bf,
                  const float* __restrict__ bc,
                  const float* __restrict__ bg,
                  float* __restrict__ out,
                  int nrows)
{
    // Packed ternary weights: wlds[g*4096 + w*128 + j], word w = signs of k=4w..4w+3
    __shared__ int   wlds[3 * 32 * 128];          // 48 KB
    __shared__ short qlds[WPB][RG][64];           // 4 KB, wave-private q rows (128 int8 each)

    const int tid  = threadIdx.x;
    const int lane = tid & 63;
    const int widx = tid >> 6;

    // ---- stage sign-packed weights into LDS (coalesced float4 reads) ----
    for (int idx = tid; idx < 3 * 4096; idx += 256) {
        const int g   = idx >> 12;
        const int rem = idx & 4095;
        const int j   = rem >> 5;
        const int w   = rem & 31;
        const float* Wp = (g == 0) ? Wf : ((g == 1) ? Wc : Wg);
        const float4 v = *(const float4*)(Wp + j * 128 + w * 4);
        const int b0 = (v.x > 0.f) - (v.x < 0.f);
        const int b1 = (v.y > 0.f) - (v.y < 0.f);
        const int b2 = (v.z > 0.f) - (v.z < 0.f);
        const int b3 = (v.w > 0.f) - (v.w < 0.f);
        wlds[g * 4096 + w * 128 + j] =
            (b0 & 0xFF) | ((b1 & 0xFF) << 8) | ((b2 & 0xFF) << 16) | ((b3 & 0xFF) << 24);
    }

    // per-lane biases for j0=2*lane, j1=2*lane+1
    const float2 vbf = *(const float2*)(bf + 2 * lane);
    const float2 vbc = *(const float2*)(bc + 2 * lane);
    const float2 vbg = *(const float2*)(bg + 2 * lane);
    __syncthreads();

    const int gw   = blockIdx.x * WPB + widx;
    const int nw   = gridDim.x * WPB;
    const int ngrp = nrows / RG;
    const long long hoff = (long long)nrows * 128;

    for (int grp = gw; grp < ngrp; grp += nw) {
        const int row0 = grp * RG;

        // ---------- quantization phase ----------
        float invs[RG];
        float2 xv[RG];
        #pragma unroll
        for (int r = 0; r < RG; ++r)
            xv[r] = *(const float2*)(x + (long long)(row0 + r) * 128 + 2 * lane);

        #pragma unroll
        for (int r = 0; r < RG; ++r) {
            float s  = xv[r].x + xv[r].y;
            float ss = xv[r].x * xv[r].x + xv[r].y * xv[r].y;
            #pragma unroll
            for (int off = 32; off >= 1; off >>= 1) {
                s  += __shfl_xor(s, off);
                ss += __shfl_xor(ss, off);
            }
            const float mean = s * (1.0f / 128.0f);
            const float var  = ss * (1.0f / 128.0f) - mean * mean;
            const float rstd = rsqrtf(var + 1e-8f);
            const float y0 = (xv[r].x - mean) * rstd;
            const float y1 = (xv[r].y - mean) * rstd;
            float a = fmaxf(fabsf(y0), fabsf(y1));
            #pragma unroll
            for (int off = 32; off >= 1; off >>= 1)
                a = fmaxf(a, __shfl_xor(a, off));
            const float sq = 127.0f / a;
            invs[r] = a * (1.0f / 127.0f);
            int q0 = (int)rintf(y0 * sq);   // v_rndne: round-half-even, matches jnp.round
            int q1 = (int)rintf(y1 * sq);
            q0 = max(-128, min(127, q0));
            q1 = max(-128, min(127, q1));
            qlds[widx][r][lane] = (short)((q0 & 0xFF) | ((q1 & 0xFF) << 8));
        }
        // ensure this wave's q writes are committed to LDS before reads below
        __asm__ __volatile__("s_waitcnt lgkmcnt(0)" ::: "memory");

        // ---------- ternary matmul phase (int8 dot4, weights reused x8 rows) ----------
        int acc[3][2][RG];
        #pragma unroll
        for (int g = 0; g < 3; ++g)
            #pragma unroll
            for (int h = 0; h < 2; ++h)
                #pragma unroll
                for (int r = 0; r < RG; ++r)
                    acc[g][h][r] = 0;

        const int* qrow = (const int*)(&qlds[widx][0][0]);   // row stride 32 words

        #pragma unroll 2
        for (int w4 = 0; w4 < 8; ++w4) {
            int qa[RG][4];
            #pragma unroll
            for (int r = 0; r < RG; ++r) {
                const int4 t = *(const int4*)(qrow + r * 32 + w4 * 4);
                qa[r][0] = t.x; qa[r][1] = t.y; qa[r][2] = t.z; qa[r][3] = t.w;
            }
            #pragma unroll
            for (int wi = 0; wi < 4; ++wi) {
                const int w = w4 * 4 + wi;
                #pragma unroll
                for (int g = 0; g < 3; ++g) {
                    const int2 wv = *(const int2*)(&wlds[g * 4096 + w * 128 + 2 * lane]);
                    #pragma unroll
                    for (int r = 0; r < RG; ++r) {
                        acc[g][0][r] = dot4(qa[r][wi], wv.x, acc[g][0][r]);
                        acc[g][1][r] = dot4(qa[r][wi], wv.y, acc[g][1][r]);
                    }
                }
            }
        }

        // ---------- epilogue: gates + state update ----------
        #pragma unroll
        for (int r = 0; r < RG; ++r) {
            const long long rbase = (long long)(row0 + r) * 128 + 2 * lane;
            const float2 hp = *(const float2*)(hprev + rbase);
            const float inv = invs[r];

            const float f0 = sigmoidf_((float)acc[0][0][r] * inv + vbf.x);
            const float f1 = sigmoidf_((float)acc[0][1][r] * inv + vbf.y);
            const float cx0 = (float)acc[1][0][r] * inv + vbc.x;
            const float cx1 = (float)acc[1][1][r] * inv + vbc.y;
            const float c0 = cx0 * sigmoidf_(cx0);   // silu
            const float c1 = cx1 * sigmoidf_(cx1);
            const float g0 = sigmoidf_((float)acc[2][0][r] * inv + vbg.x);
            const float g1 = sigmoidf_((float)acc[2][1][r] * inv + vbg.y);

            const float h0 = f0 * hp.x + (1.0f - f0) * c0;
            const float h1 = f1 * hp.y + (1.0f - f1) * c1;
            const float o0 = g0 * h0;
            const float o1 = g1 * h1;

            *(float2*)(out + rbase)        = make_float2(o0, o1);
            *(float2*)(out + hoff + rbase) = make_float2(h0, h1);
        }
    }
}

extern "C" void kernel_launch(void* const* d_in, const int* in_sizes, int n_in,
                              void* d_out, int out_size, void* d_ws, size_t ws_size,
                              hipStream_t stream) {
    const float* x  = (const float*)d_in[0];
    const float* h  = (const float*)d_in[1];
    const float* Wf = (const float*)d_in[2];
    const float* Wc = (const float*)d_in[3];
    const float* Wg = (const float*)d_in[4];
    const float* bf = (const float*)d_in[5];
    const float* bc = (const float*)d_in[6];
    const float* bg = (const float*)d_in[7];
    float* out = (float*)d_out;
    const int nrows = in_sizes[0] / 128;   // B

    hipLaunchKernelGGL(mlgru_kernel, dim3(768), dim3(256), 0, stream,
                       x, h, Wf, Wc, Wg, bf, bc, bg, out, nrows);
}